// Round 14
// baseline (93.018 us; speedup 1.0000x reference)
//
#include <hip/hip_runtime.h>
#include <hip/hip_bf16.h>

#define B_ 512
#define T_ 1024
#define N_ 64
#define NA_ 66
#define K_ 128
#define BURN 3
#define LN2 0.69314718055994530942f

typedef __attribute__((ext_vector_type(8))) short short8;
typedef __attribute__((ext_vector_type(4))) float f32x4;

__device__ __forceinline__ unsigned short bf16_rne(float f) {
    unsigned u = __float_as_uint(f);
    u += 0x7fffu + ((u >> 16) & 1u);
    return (unsigned short)(u >> 16);
}
__device__ __forceinline__ int pack2(float a, float b) {
    __hip_bfloat162 h = __float22bfloat162_rn(make_float2(a, b)); // x -> low
    int r; __builtin_memcpy(&r, &h, 4); return r;
}

__global__ __launch_bounds__(512, 4) void crf_mc128(
    const int* __restrict__ y,      // [B,T]
    const float* __restrict__ P,    // [B,T,N]
    const int* __restrict__ lens,   // [B]
    const float* __restrict__ A,    // [NA,NA]
    float* __restrict__ out)        // [B]
{
    const int b = blockIdx.x;
    const int tid = threadIdx.x;
    const int w = tid >> 6;         // wave 0..7: owns global chains 16w .. 16w+15
    const int l = tid & 63;
    const int g = l >> 4;           // k-group / C row-group
    const int m = l & 15;           // A-row (read side) / C col-pos
    const long pbase = (long)b * (T_ * N_);
    const int yb = b * T_;
    const int len = lens[b];        // in [512, 1024]
    const int n = len - 1;          // scan steps 511..1023
    const int L = (n + K_ - 1) / K_;            // owned steps per chain (4..8)
    const int Epad = ((L + BURN) + 3) & ~3;     // executed lockstep steps, padded

    // B-frags: B1[q][e] = W[8g+e][4m+q]*2^-6 (W = exp(Asub)); B2 rows 32+8g+e.
    short8 B1[4], B2[4];
#pragma unroll
    for (int q = 0; q < 4; ++q) {
        const int col = 4 * m + q;
#pragma unroll
        for (int e = 0; e < 8; ++e) {
            B1[q][e] = (short)bf16_rne(__expf(A[(8 * g + e) * NA_ + col]) * 0.015625f);
            B2[q][e] = (short)bf16_rne(__expf(A[(32 + 8 * g + e) * NA_ + col]) * 0.015625f);
        }
    }

    __shared__ __align__(16) unsigned char zb[8][2048];  // per-wave z[16][64] bf16
    __shared__ float gsh[8];
    __shared__ float psh[8];
    unsigned char* zbw = zb[w];

    // LDS: granule (8 states = 16 B) XOR-swizzled by (chain&7)  [r10-proven]
    const int roff1 = m * 128 + 16 * (g ^ (m & 7));
    const int roff2 = m * 128 + 16 * ((g + 4) ^ (m & 7));
    int woff[4], t0_[4], ue[4];
#pragma unroll
    for (int dr = 0; dr < 4; ++dr) {
        const int i = 4 * g + dr;           // local chain (write/scale side)
        const int c = 16 * w + i;           // global chain
        woff[dr] = i * 128 + 16 * ((m >> 1) ^ (i & 7)) + 8 * (m & 1);
        t0_[dr] = c ? (c * L - (BURN - 1)) : 1;
        const int tend = min((c + 1) * L, n);
        ue[dr] = (c == 0) ? (L - 1)
               : ((c * L >= n) ? (BURN - 1) : (BURN - 1 + tend - c * L));
    }

    const float4* __restrict__ p4 = (const float4*)(P + pbase);

    // init z: global chain 0 = exp(A[START,:]+P[0,:]) exact; others uniform 1
    {
        const float4 p0 = p4[m];
        const float v0 = __expf(A[N_ * NA_ + 4 * m + 0] + p0.x);
        const float v1 = __expf(A[N_ * NA_ + 4 * m + 1] + p0.y);
        const float v2 = __expf(A[N_ * NA_ + 4 * m + 2] + p0.z);
        const float v3 = __expf(A[N_ * NA_ + 4 * m + 3] + p0.w);
#pragma unroll
        for (int dr = 0; dr < 4; ++dr) {
            const bool c0 = (w == 0 && g == 0 && dr == 0);
            int2 wv;
            wv.x = pack2(c0 ? v0 : 1.0f, c0 ? v1 : 1.0f);
            wv.y = pack2(c0 ? v2 : 1.0f, c0 ? v3 : 1.0f);
            __builtin_memcpy(zbw + woff[dr], &wv, 8);
        }
    }

    float4 rbuf[4][4];                  // prefetch ring [slot][dr], distance 4
#pragma unroll
    for (int du = 0; du < 4; ++du)
#pragma unroll
        for (int dr = 0; dr < 4; ++dr) {
            int t = t0_[dr] + du; t = t < (T_ - 1) ? t : (T_ - 1);
            rbuf[du][dr] = p4[t * 16 + m];
        }

    float chk[4][4], endv[4][4];
#pragma unroll
    for (int dr = 0; dr < 4; ++dr)
#pragma unroll
        for (int q = 0; q < 4; ++q) { chk[dr][q] = 1.0f; endv[dr][q] = 1.0f; }

    for (int ub = 0; ub < Epad; ub += 4) {
#pragma unroll
        for (int du = 0; du < 4; ++du) {
            const int u = ub + du;
            float ep[4][4];
#pragma unroll
            for (int dr = 0; dr < 4; ++dr) {
                const float4 pv = rbuf[du][dr];
                ep[dr][0] = __expf(pv.x); ep[dr][1] = __expf(pv.y);
                ep[dr][2] = __expf(pv.z); ep[dr][3] = __expf(pv.w);
            }
            short8 a1, a2;
            __builtin_memcpy(&a1, zbw + roff1, 16);
            __builtin_memcpy(&a2, zbw + roff2, 16);
            const f32x4 zc = {0.f, 0.f, 0.f, 0.f};
            f32x4 acc0 = __builtin_amdgcn_mfma_f32_16x16x32_bf16(a1, B1[0], zc, 0, 0, 0);
            acc0 = __builtin_amdgcn_mfma_f32_16x16x32_bf16(a2, B2[0], acc0, 0, 0, 0);
            f32x4 acc1 = __builtin_amdgcn_mfma_f32_16x16x32_bf16(a1, B1[1], zc, 0, 0, 0);
            acc1 = __builtin_amdgcn_mfma_f32_16x16x32_bf16(a2, B2[1], acc1, 0, 0, 0);
            f32x4 acc2 = __builtin_amdgcn_mfma_f32_16x16x32_bf16(a1, B1[2], zc, 0, 0, 0);
            acc2 = __builtin_amdgcn_mfma_f32_16x16x32_bf16(a2, B2[2], acc2, 0, 0, 0);
            f32x4 acc3 = __builtin_amdgcn_mfma_f32_16x16x32_bf16(a1, B1[3], zc, 0, 0, 0);
            acc3 = __builtin_amdgcn_mfma_f32_16x16x32_bf16(a2, B2[3], acc3, 0, 0, 0);
            float cur[4][4];
#pragma unroll
            for (int dr = 0; dr < 4; ++dr) {
                cur[dr][0] = acc0[dr] * ep[dr][0];
                cur[dr][1] = acc1[dr] * ep[dr][1];
                cur[dr][2] = acc2[dr] * ep[dr][2];
                cur[dr][3] = acc3[dr] * ep[dr][3];
            }
            if (u == BURN - 1) {                 // uniform: checkpoint capture
#pragma unroll
                for (int dr = 0; dr < 4; ++dr)
#pragma unroll
                    for (int q = 0; q < 4; ++q) chk[dr][q] = cur[dr][q];
            }
#pragma unroll
            for (int dr = 0; dr < 4; ++dr) {     // per-chain end capture (cndmask)
                const bool hit = (u == ue[dr]);
#pragma unroll
                for (int q = 0; q < 4; ++q)
                    endv[dr][q] = hit ? cur[dr][q] : endv[dr][q];
            }
#pragma unroll
            for (int dr = 0; dr < 4; ++dr) {     // pack + swizzled write of next z
                int2 wv;
                wv.x = pack2(cur[dr][0], cur[dr][1]);
                wv.y = pack2(cur[dr][2], cur[dr][3]);
                __builtin_memcpy(zbw + woff[dr], &wv, 8);
            }
#pragma unroll
            for (int dr = 0; dr < 4; ++dr) {     // prefetch u+4
                int t = t0_[dr] + u + 4; t = t < (T_ - 1) ? t : (T_ - 1);
                rbuf[du][dr] = p4[t * 16 + m];
            }
        }
    }

    // ---- per-wave combine: telescoping log-gains ----
    const float wE0 = __expf(A[(4 * m + 0) * NA_ + (N_ + 1)]);
    const float wE1 = __expf(A[(4 * m + 1) * NA_ + (N_ + 1)]);
    const float wE2 = __expf(A[(4 * m + 2) * NA_ + (N_ + 1)]);
    const float wE3 = __expf(A[(4 * m + 3) * NA_ + (N_ + 1)]);
    float se[4], sk[4], swe[4];
#pragma unroll
    for (int dr = 0; dr < 4; ++dr) {
        se[dr] = (endv[dr][0] + endv[dr][1]) + (endv[dr][2] + endv[dr][3]);
        sk[dr] = (chk[dr][0] + chk[dr][1]) + (chk[dr][2] + chk[dr][3]);
        swe[dr] = endv[dr][0] * wE0 + endv[dr][1] * wE1
                + endv[dr][2] * wE2 + endv[dr][3] * wE3;
    }
#pragma unroll
    for (int off = 1; off <= 8; off <<= 1) {
#pragma unroll
        for (int dr = 0; dr < 4; ++dr) {
            se[dr]  += __shfl_xor(se[dr],  off, 64);
            sk[dr]  += __shfl_xor(sk[dr],  off, 64);
            swe[dr] += __shfl_xor(swe[dr], off, 64);
        }
    }
    float contrib = 0.f;
#pragma unroll
    for (int dr = 0; dr < 4; ++dr) {
        const int c = 16 * w + 4 * g + dr;
        const bool isfin = (c * L < n) && (min((c + 1) * L, n) == n);
        contrib += isfin ? __logf(swe[dr]) : __logf(se[dr]);
        contrib -= (c >= 1) ? __logf(sk[dr]) : 0.f;
    }
    contrib += __shfl_xor(contrib, 16, 64);   // sum the 4 g-groups (1 lane each)
    contrib += __shfl_xor(contrib, 32, 64);
    if (l == 0) gsh[w] = contrib;

    // ---- score partials: 512 threads x 2 timesteps ----
    float sc = 0.f;
#pragma unroll
    for (int kk = 0; kk < 2; ++kk) {
        const int t = tid + 512 * kk;         // 0..1023
        const int yt = y[yb + t];
        const bool v = t < len;
        sc += v ? P[pbase + (long)t * N_ + yt] : 0.f;
        sc += (v && t >= 1) ? A[y[yb + t - 1] * NA_ + yt] : 0.f;
    }
#pragma unroll
    for (int off = 32; off >= 1; off >>= 1)
        sc += __shfl_xor(sc, off, 64);
    if (l == 0) psh[w] = sc;
    __syncthreads();

    if (tid == 0) {
        float logZ = 6.0f * LN2 * (float)n;
        float score = A[N_ * NA_ + y[yb]]
                    + A[y[yb + len - 1] * NA_ + (N_ + 1)];
#pragma unroll
        for (int q = 0; q < 8; ++q) { logZ += gsh[q]; score += psh[q]; }
        out[b] = logZ - score;
    }
}

extern "C" void kernel_launch(void* const* d_in, const int* in_sizes, int n_in,
                              void* d_out, int out_size, void* d_ws, size_t ws_size,
                              hipStream_t stream) {
    const int* y = (const int*)d_in[0];
    const float* P = (const float*)d_in[1];
    const int* lens = (const int*)d_in[2];
    const float* A = (const float*)d_in[3];
    float* out = (float*)d_out;
    crf_mc128<<<dim3(B_), dim3(512), 0, stream>>>(y, P, lens, A, out);
}

// Round 15
// 48.687 us; speedup vs baseline: 1.9105x; 1.9105x over previous
//
#include <hip/hip_runtime.h>
#include <hip/hip_bf16.h>

#define B_ 512
#define T_ 1024
#define N_ 64
#define NA_ 66
#define K_ 128
#define BURN 3
#define LN2 0.69314718055994530942f

typedef __attribute__((ext_vector_type(8))) short short8;
typedef __attribute__((ext_vector_type(4))) float f32x4;

__device__ __forceinline__ unsigned short bf16_rne(float f) {
    unsigned u = __float_as_uint(f);
    u += 0x7fffu + ((u >> 16) & 1u);
    return (unsigned short)(u >> 16);
}
__device__ __forceinline__ int pack2(float a, float b) {
    __hip_bfloat162 h = __float22bfloat162_rn(make_float2(a, b)); // x -> low
    int r; __builtin_memcpy(&r, &h, 4); return r;
}

__global__ __launch_bounds__(512, 2) void crf_mc128(
    const int* __restrict__ y,      // [B,T]
    const float* __restrict__ P,    // [B,T,N]
    const int* __restrict__ lens,   // [B]
    const float* __restrict__ A,    // [NA,NA]
    float* __restrict__ out)        // [B]
{
    const int b = blockIdx.x;
    const int tid = threadIdx.x;
    const int w = tid >> 6;         // wave 0..7: owns global chains 16w .. 16w+15
    const int l = tid & 63;
    const int g = l >> 4;           // k-group / C row-group
    const int m = l & 15;           // A-row (read side) / C col-pos
    const long pbase = (long)b * (T_ * N_);
    const int yb = b * T_;
    const int len = lens[b];        // in [512, 1024]
    const int n = len - 1;          // scan steps 511..1023
    const int L = (n + K_ - 1) / K_;            // owned steps per chain (4..8)
    const int Epad = ((L + BURN) + 3) & ~3;     // executed lockstep steps, padded

    // B-frags: B1[q][e] = W[8g+e][4m+q]*2^-6 (W = exp(Asub)); B2 rows 32+8g+e.
    short8 B1[4], B2[4];
#pragma unroll
    for (int q = 0; q < 4; ++q) {
        const int col = 4 * m + q;
#pragma unroll
        for (int e = 0; e < 8; ++e) {
            B1[q][e] = (short)bf16_rne(__expf(A[(8 * g + e) * NA_ + col]) * 0.015625f);
            B2[q][e] = (short)bf16_rne(__expf(A[(32 + 8 * g + e) * NA_ + col]) * 0.015625f);
        }
    }

    __shared__ __align__(16) unsigned char zb[8][2048];  // per-wave z[16][64] bf16
    __shared__ float gsh[8];
    __shared__ float psh[8];
    unsigned char* zbw = zb[w];

    // LDS: granule (8 states = 16 B) XOR-swizzled by (chain&7)  [r10-proven]
    const int roff1 = m * 128 + 16 * (g ^ (m & 7));
    const int roff2 = m * 128 + 16 * ((g + 4) ^ (m & 7));
    int woff[4], t0_[4], ue[4];
#pragma unroll
    for (int dr = 0; dr < 4; ++dr) {
        const int i = 4 * g + dr;           // local chain (write/scale side)
        const int c = 16 * w + i;           // global chain
        woff[dr] = i * 128 + 16 * ((m >> 1) ^ (i & 7)) + 8 * (m & 1);
        t0_[dr] = c ? (c * L - (BURN - 1)) : 1;
        const int tend = min((c + 1) * L, n);
        ue[dr] = (c == 0) ? (L - 1)
               : ((c * L >= n) ? (BURN - 1) : (BURN - 1 + tend - c * L));
    }

    const float4* __restrict__ p4 = (const float4*)(P + pbase);

    // init z: global chain 0 = exp(A[START,:]+P[0,:]) exact; others uniform 1
    {
        const float4 p0 = p4[m];
        const float v0 = __expf(A[N_ * NA_ + 4 * m + 0] + p0.x);
        const float v1 = __expf(A[N_ * NA_ + 4 * m + 1] + p0.y);
        const float v2 = __expf(A[N_ * NA_ + 4 * m + 2] + p0.z);
        const float v3 = __expf(A[N_ * NA_ + 4 * m + 3] + p0.w);
#pragma unroll
        for (int dr = 0; dr < 4; ++dr) {
            const bool c0 = (w == 0 && g == 0 && dr == 0);
            int2 wv;
            wv.x = pack2(c0 ? v0 : 1.0f, c0 ? v1 : 1.0f);
            wv.y = pack2(c0 ? v2 : 1.0f, c0 ? v3 : 1.0f);
            __builtin_memcpy(zbw + woff[dr], &wv, 8);
        }
    }

    float4 rbuf[4][4];                  // prefetch ring [slot][dr], distance 4
#pragma unroll
    for (int du = 0; du < 4; ++du)
#pragma unroll
        for (int dr = 0; dr < 4; ++dr) {
            int t = t0_[dr] + du; t = t < (T_ - 1) ? t : (T_ - 1);
            rbuf[du][dr] = p4[t * 16 + m];
        }

    float chk[4][4], endv[4][4];
#pragma unroll
    for (int dr = 0; dr < 4; ++dr)
#pragma unroll
        for (int q = 0; q < 4; ++q) { chk[dr][q] = 1.0f; endv[dr][q] = 1.0f; }

    for (int ub = 0; ub < Epad; ub += 4) {
#pragma unroll
        for (int du = 0; du < 4; ++du) {
            const int u = ub + du;
            float ep[4][4];
#pragma unroll
            for (int dr = 0; dr < 4; ++dr) {
                const float4 pv = rbuf[du][dr];
                ep[dr][0] = __expf(pv.x); ep[dr][1] = __expf(pv.y);
                ep[dr][2] = __expf(pv.z); ep[dr][3] = __expf(pv.w);
            }
            short8 a1, a2;
            __builtin_memcpy(&a1, zbw + roff1, 16);
            __builtin_memcpy(&a2, zbw + roff2, 16);
            const f32x4 zc = {0.f, 0.f, 0.f, 0.f};
            f32x4 acc0 = __builtin_amdgcn_mfma_f32_16x16x32_bf16(a1, B1[0], zc, 0, 0, 0);
            acc0 = __builtin_amdgcn_mfma_f32_16x16x32_bf16(a2, B2[0], acc0, 0, 0, 0);
            f32x4 acc1 = __builtin_amdgcn_mfma_f32_16x16x32_bf16(a1, B1[1], zc, 0, 0, 0);
            acc1 = __builtin_amdgcn_mfma_f32_16x16x32_bf16(a2, B2[1], acc1, 0, 0, 0);
            f32x4 acc2 = __builtin_amdgcn_mfma_f32_16x16x32_bf16(a1, B1[2], zc, 0, 0, 0);
            acc2 = __builtin_amdgcn_mfma_f32_16x16x32_bf16(a2, B2[2], acc2, 0, 0, 0);
            f32x4 acc3 = __builtin_amdgcn_mfma_f32_16x16x32_bf16(a1, B1[3], zc, 0, 0, 0);
            acc3 = __builtin_amdgcn_mfma_f32_16x16x32_bf16(a2, B2[3], acc3, 0, 0, 0);
            float cur[4][4];
#pragma unroll
            for (int dr = 0; dr < 4; ++dr) {
                cur[dr][0] = acc0[dr] * ep[dr][0];
                cur[dr][1] = acc1[dr] * ep[dr][1];
                cur[dr][2] = acc2[dr] * ep[dr][2];
                cur[dr][3] = acc3[dr] * ep[dr][3];
            }
            if (u == BURN - 1) {                 // uniform: checkpoint capture
#pragma unroll
                for (int dr = 0; dr < 4; ++dr)
#pragma unroll
                    for (int q = 0; q < 4; ++q) chk[dr][q] = cur[dr][q];
            }
#pragma unroll
            for (int dr = 0; dr < 4; ++dr) {     // per-chain end capture (cndmask)
                const bool hit = (u == ue[dr]);
#pragma unroll
                for (int q = 0; q < 4; ++q)
                    endv[dr][q] = hit ? cur[dr][q] : endv[dr][q];
            }
#pragma unroll
            for (int dr = 0; dr < 4; ++dr) {     // pack + swizzled write of next z
                int2 wv;
                wv.x = pack2(cur[dr][0], cur[dr][1]);
                wv.y = pack2(cur[dr][2], cur[dr][3]);
                __builtin_memcpy(zbw + woff[dr], &wv, 8);
            }
#pragma unroll
            for (int dr = 0; dr < 4; ++dr) {     // prefetch u+4
                int t = t0_[dr] + u + 4; t = t < (T_ - 1) ? t : (T_ - 1);
                rbuf[du][dr] = p4[t * 16 + m];
            }
        }
    }

    // ---- per-wave combine: telescoping log-gains ----
    const float wE0 = __expf(A[(4 * m + 0) * NA_ + (N_ + 1)]);
    const float wE1 = __expf(A[(4 * m + 1) * NA_ + (N_ + 1)]);
    const float wE2 = __expf(A[(4 * m + 2) * NA_ + (N_ + 1)]);
    const float wE3 = __expf(A[(4 * m + 3) * NA_ + (N_ + 1)]);
    float se[4], sk[4], swe[4];
#pragma unroll
    for (int dr = 0; dr < 4; ++dr) {
        se[dr] = (endv[dr][0] + endv[dr][1]) + (endv[dr][2] + endv[dr][3]);
        sk[dr] = (chk[dr][0] + chk[dr][1]) + (chk[dr][2] + chk[dr][3]);
        swe[dr] = endv[dr][0] * wE0 + endv[dr][1] * wE1
                + endv[dr][2] * wE2 + endv[dr][3] * wE3;
    }
#pragma unroll
    for (int off = 1; off <= 8; off <<= 1) {
#pragma unroll
        for (int dr = 0; dr < 4; ++dr) {
            se[dr]  += __shfl_xor(se[dr],  off, 64);
            sk[dr]  += __shfl_xor(sk[dr],  off, 64);
            swe[dr] += __shfl_xor(swe[dr], off, 64);
        }
    }
    float contrib = 0.f;
#pragma unroll
    for (int dr = 0; dr < 4; ++dr) {
        const int c = 16 * w + 4 * g + dr;
        const bool isfin = (c * L < n) && (min((c + 1) * L, n) == n);
        contrib += isfin ? __logf(swe[dr]) : __logf(se[dr]);
        contrib -= (c >= 1) ? __logf(sk[dr]) : 0.f;
    }
    contrib += __shfl_xor(contrib, 16, 64);   // sum the 4 g-groups (1 lane each)
    contrib += __shfl_xor(contrib, 32, 64);
    if (l == 0) gsh[w] = contrib;

    // ---- score partials: 512 threads x 2 timesteps ----
    float sc = 0.f;
#pragma unroll
    for (int kk = 0; kk < 2; ++kk) {
        const int t = tid + 512 * kk;         // 0..1023
        const int yt = y[yb + t];
        const bool v = t < len;
        sc += v ? P[pbase + (long)t * N_ + yt] : 0.f;
        sc += (v && t >= 1) ? A[y[yb + t - 1] * NA_ + yt] : 0.f;
    }
#pragma unroll
    for (int off = 32; off >= 1; off >>= 1)
        sc += __shfl_xor(sc, off, 64);
    if (l == 0) psh[w] = sc;
    __syncthreads();

    if (tid == 0) {
        float logZ = 6.0f * LN2 * (float)n;
        float score = A[N_ * NA_ + y[yb]]
                    + A[y[yb + len - 1] * NA_ + (N_ + 1)];
#pragma unroll
        for (int q = 0; q < 8; ++q) { logZ += gsh[q]; score += psh[q]; }
        out[b] = logZ - score;
    }
}

extern "C" void kernel_launch(void* const* d_in, const int* in_sizes, int n_in,
                              void* d_out, int out_size, void* d_ws, size_t ws_size,
                              hipStream_t stream) {
    const int* y = (const int*)d_in[0];
    const float* P = (const float*)d_in[1];
    const int* lens = (const int*)d_in[2];
    const float* A = (const float*)d_in[3];
    float* out = (float*)d_out;
    crf_mc128<<<dim3(B_), dim3(512), 0, stream>>>(y, P, lens, A, out);
}

// Round 16
// 31.954 us; speedup vs baseline: 2.9110x; 1.5237x over previous
//
#include <hip/hip_runtime.h>
#include <hip/hip_bf16.h>

#define B_ 512
#define T_ 1024
#define N_ 64
#define NA_ 66
#define K_ 64
#define BURN 4
#define LN2 0.69314718055994530942f

typedef __attribute__((ext_vector_type(8))) short short8;
typedef __attribute__((ext_vector_type(4))) float f32x4;

__device__ __forceinline__ unsigned short bf16_rne(float f) {
    unsigned u = __float_as_uint(f);
    u += 0x7fffu + ((u >> 16) & 1u);
    return (unsigned short)(u >> 16);
}
__device__ __forceinline__ int pack2(float a, float b) {
    __hip_bfloat162 h = __float22bfloat162_rn(make_float2(a, b)); // x -> low
    int r; __builtin_memcpy(&r, &h, 4); return r;
}

__global__ __launch_bounds__(256) void crf_mc64(
    const int* __restrict__ y,      // [B,T]
    const float* __restrict__ P,    // [B,T,N]
    const int* __restrict__ lens,   // [B]
    const float* __restrict__ A,    // [NA,NA]
    float* __restrict__ out)        // [B]
{
    const int b = blockIdx.x;
    const int tid = threadIdx.x;
    const int w = tid >> 6;         // wave 0..3: owns global chains 16w .. 16w+15
    const int l = tid & 63;
    const int g = l >> 4;           // k-group / C row-group
    const int m = l & 15;           // A-row (read side) / C col-pos
    const long pbase = (long)b * (T_ * N_);
    const int yb = b * T_;
    const int len = lens[b];        // in [512, 1024]
    const int n = len - 1;          // scan steps 511..1023
    const int L = (n + K_ - 1) / K_;            // owned steps per chain (8..16)
    const int Epad = ((L + BURN) + 3) & ~3;     // executed lockstep steps, padded
    const int nblk = Epad >> 2;                 // 4-step blocks

    // B-frags: B1[q][e] = W[8g+e][4m+q]*2^-6 (W = exp(Asub)); B2 rows 32+8g+e.
    short8 B1[4], B2[4];
#pragma unroll
    for (int q = 0; q < 4; ++q) {
        const int col = 4 * m + q;
#pragma unroll
        for (int e = 0; e < 8; ++e) {
            B1[q][e] = (short)bf16_rne(__expf(A[(8 * g + e) * NA_ + col]) * 0.015625f);
            B2[q][e] = (short)bf16_rne(__expf(A[(32 + 8 * g + e) * NA_ + col]) * 0.015625f);
        }
    }

    __shared__ __align__(16) unsigned char zb[4][2048];    // per-wave z[16][64] bf16
    __shared__ __align__(16) float pst[4][2][4][4][64];    // [wave][slot][dr][row][elem]
    __shared__ float gsh[4];
    __shared__ float psh[4];
    unsigned char* zbw = zb[w];

    // LDS z: granule (8 states = 16 B) XOR-swizzled by (chain&7)  [r10-proven]
    const int roff1 = m * 128 + 16 * (g ^ (m & 7));
    const int roff2 = m * 128 + 16 * ((g + 4) ^ (m & 7));
    int woff[4], t0_[4], ue[4];
#pragma unroll
    for (int dr = 0; dr < 4; ++dr) {
        const int i = 4 * g + dr;           // local chain (write/scale side)
        const int c = 16 * w + i;           // global chain
        woff[dr] = i * 128 + 16 * ((m >> 1) ^ (i & 7)) + 8 * (m & 1);
        t0_[dr] = c ? (c * L - (BURN - 1)) : 1;
        const int tend = min((c + 1) * L, n);
        ue[dr] = (c == 0) ? (L - 1)
               : ((c * L >= n) ? (BURN - 1) : (BURN - 1 + tend - c * L));
    }

    const float4* __restrict__ p4 = (const float4*)(P + pbase);

    // dense row loads: one instr = 4 consecutive rows of chain-group dr (1 KB unique)
    const int lrow = l >> 4;            // which of the 4 rows this lane fetches
    const int lelm = l & 15;            // float4 index within the row
    auto ldrow = [&](int blk, int dr) -> float4 {
        int t = t0_[dr] + 4 * blk + lrow;
        t = t < (T_ - 1) ? t : (T_ - 1);
        return p4[(long)t * 16 + lelm];
    };
    auto stwr = [&](int sl, int dr, float4 v) {
        *reinterpret_cast<float4*>(&pst[w][sl][dr][lrow][4 * lelm]) = v;
    };

    // init z: global chain 0 = exp(A[START,:]+P[0,:]) exact; others uniform 1
    {
        const float4 p0 = p4[m];
        const float v0 = __expf(A[N_ * NA_ + 4 * m + 0] + p0.x);
        const float v1 = __expf(A[N_ * NA_ + 4 * m + 1] + p0.y);
        const float v2 = __expf(A[N_ * NA_ + 4 * m + 2] + p0.z);
        const float v3 = __expf(A[N_ * NA_ + 4 * m + 3] + p0.w);
#pragma unroll
        for (int dr = 0; dr < 4; ++dr) {
            const bool c0 = (w == 0 && g == 0 && dr == 0);
            int2 wv;
            wv.x = pack2(c0 ? v0 : 1.0f, c0 ? v1 : 1.0f);
            wv.y = pack2(c0 ? v2 : 1.0f, c0 ? v3 : 1.0f);
            __builtin_memcpy(zbw + woff[dr], &wv, 8);
        }
    }

    float chk[4][4], endv[4][4];
#pragma unroll
    for (int dr = 0; dr < 4; ++dr)
#pragma unroll
        for (int q = 0; q < 4; ++q) { chk[dr][q] = 1.0f; endv[dr][q] = 1.0f; }

    // one lockstep step: P row comes from staged LDS slot sl, sub-row du
    auto step = [&](int u, int sl, int du) {
        float ep[4][4];
#pragma unroll
        for (int dr = 0; dr < 4; ++dr) {
            float4 pv;
            __builtin_memcpy(&pv, &pst[w][sl][dr][du][4 * m], 16);
            ep[dr][0] = __expf(pv.x); ep[dr][1] = __expf(pv.y);
            ep[dr][2] = __expf(pv.z); ep[dr][3] = __expf(pv.w);
        }
        short8 a1, a2;
        __builtin_memcpy(&a1, zbw + roff1, 16);
        __builtin_memcpy(&a2, zbw + roff2, 16);
        const f32x4 zc = {0.f, 0.f, 0.f, 0.f};
        f32x4 acc0 = __builtin_amdgcn_mfma_f32_16x16x32_bf16(a1, B1[0], zc, 0, 0, 0);
        acc0 = __builtin_amdgcn_mfma_f32_16x16x32_bf16(a2, B2[0], acc0, 0, 0, 0);
        f32x4 acc1 = __builtin_amdgcn_mfma_f32_16x16x32_bf16(a1, B1[1], zc, 0, 0, 0);
        acc1 = __builtin_amdgcn_mfma_f32_16x16x32_bf16(a2, B2[1], acc1, 0, 0, 0);
        f32x4 acc2 = __builtin_amdgcn_mfma_f32_16x16x32_bf16(a1, B1[2], zc, 0, 0, 0);
        acc2 = __builtin_amdgcn_mfma_f32_16x16x32_bf16(a2, B2[2], acc2, 0, 0, 0);
        f32x4 acc3 = __builtin_amdgcn_mfma_f32_16x16x32_bf16(a1, B1[3], zc, 0, 0, 0);
        acc3 = __builtin_amdgcn_mfma_f32_16x16x32_bf16(a2, B2[3], acc3, 0, 0, 0);
        float cur[4][4];
#pragma unroll
        for (int dr = 0; dr < 4; ++dr) {
            cur[dr][0] = acc0[dr] * ep[dr][0];
            cur[dr][1] = acc1[dr] * ep[dr][1];
            cur[dr][2] = acc2[dr] * ep[dr][2];
            cur[dr][3] = acc3[dr] * ep[dr][3];
        }
        if (u == BURN - 1) {                 // uniform: checkpoint capture
#pragma unroll
            for (int dr = 0; dr < 4; ++dr)
#pragma unroll
                for (int q = 0; q < 4; ++q) chk[dr][q] = cur[dr][q];
        }
#pragma unroll
        for (int dr = 0; dr < 4; ++dr) {     // per-chain end capture (cndmask)
            const bool hit = (u == ue[dr]);
#pragma unroll
            for (int q = 0; q < 4; ++q)
                endv[dr][q] = hit ? cur[dr][q] : endv[dr][q];
        }
#pragma unroll
        for (int dr = 0; dr < 4; ++dr) {     // pack + swizzled write of next z
            int2 wv;
            wv.x = pack2(cur[dr][0], cur[dr][1]);
            wv.y = pack2(cur[dr][2], cur[dr][3]);
            __builtin_memcpy(zbw + woff[dr], &wv, 8);
        }
    };

    // prologue: stage block 0, load block 1
    float4 pend0, pend1, pend2, pend3;
    stwr(0, 0, ldrow(0, 0)); stwr(0, 1, ldrow(0, 1));
    stwr(0, 2, ldrow(0, 2)); stwr(0, 3, ldrow(0, 3));
    pend0 = ldrow(1, 0); pend1 = ldrow(1, 1);
    pend2 = ldrow(1, 2); pend3 = ldrow(1, 3);

    for (int blk = 0; blk < nblk; ++blk) {
        const int sl = blk & 1;
        // write block blk+1 into the other slot; issue loads for blk+2
        stwr(sl ^ 1, 0, pend0); stwr(sl ^ 1, 1, pend1);
        stwr(sl ^ 1, 2, pend2); stwr(sl ^ 1, 3, pend3);
        pend0 = ldrow(blk + 2, 0); pend1 = ldrow(blk + 2, 1);
        pend2 = ldrow(blk + 2, 2); pend3 = ldrow(blk + 2, 3);
#pragma unroll
        for (int du = 0; du < 4; ++du)
            step(4 * blk + du, sl, du);
    }

    // ---- per-wave combine: telescoping log-gains ----
    const float wE0 = __expf(A[(4 * m + 0) * NA_ + (N_ + 1)]);
    const float wE1 = __expf(A[(4 * m + 1) * NA_ + (N_ + 1)]);
    const float wE2 = __expf(A[(4 * m + 2) * NA_ + (N_ + 1)]);
    const float wE3 = __expf(A[(4 * m + 3) * NA_ + (N_ + 1)]);
    float se[4], sk[4], swe[4];
#pragma unroll
    for (int dr = 0; dr < 4; ++dr) {
        se[dr] = (endv[dr][0] + endv[dr][1]) + (endv[dr][2] + endv[dr][3]);
        sk[dr] = (chk[dr][0] + chk[dr][1]) + (chk[dr][2] + chk[dr][3]);
        swe[dr] = endv[dr][0] * wE0 + endv[dr][1] * wE1
                + endv[dr][2] * wE2 + endv[dr][3] * wE3;
    }
#pragma unroll
    for (int off = 1; off <= 8; off <<= 1) {
#pragma unroll
        for (int dr = 0; dr < 4; ++dr) {
            se[dr]  += __shfl_xor(se[dr],  off, 64);
            sk[dr]  += __shfl_xor(sk[dr],  off, 64);
            swe[dr] += __shfl_xor(swe[dr], off, 64);
        }
    }
    float contrib = 0.f;
#pragma unroll
    for (int dr = 0; dr < 4; ++dr) {
        const int c = 16 * w + 4 * g + dr;
        const bool isfin = (c * L < n) && (min((c + 1) * L, n) == n);
        contrib += isfin ? __logf(swe[dr]) : __logf(se[dr]);
        contrib -= (c >= 1) ? __logf(sk[dr]) : 0.f;
    }
    contrib += __shfl_xor(contrib, 16, 64);   // sum the 4 g-groups (1 lane each)
    contrib += __shfl_xor(contrib, 32, 64);
    if (l == 0) gsh[w] = contrib;

    // ---- score partials: 256 threads x 4 timesteps ----
    float sc = 0.f;
#pragma unroll
    for (int kk = 0; kk < 4; ++kk) {
        const int t = tid + 256 * kk;         // 0..1023
        const int yt = y[yb + t];
        const bool v = t < len;
        sc += v ? P[pbase + (long)t * N_ + yt] : 0.f;
        sc += (v && t >= 1) ? A[y[yb + t - 1] * NA_ + yt] : 0.f;
    }
#pragma unroll
    for (int off = 32; off >= 1; off >>= 1)
        sc += __shfl_xor(sc, off, 64);
    if (l == 0) psh[w] = sc;
    __syncthreads();

    if (tid == 0) {
        const float logZ = gsh[0] + gsh[1] + gsh[2] + gsh[3]
                         + 6.0f * LN2 * (float)n;
        const float score = psh[0] + psh[1] + psh[2] + psh[3]
                          + A[N_ * NA_ + y[yb]]
                          + A[y[yb + len - 1] * NA_ + (N_ + 1)];
        out[b] = logZ - score;
    }
}

extern "C" void kernel_launch(void* const* d_in, const int* in_sizes, int n_in,
                              void* d_out, int out_size, void* d_ws, size_t ws_size,
                              hipStream_t stream) {
    const int* y = (const int*)d_in[0];
    const float* P = (const float*)d_in[1];
    const int* lens = (const int*)d_in[2];
    const float* A = (const float*)d_in[3];
    float* out = (float*)d_out;
    crf_mc64<<<dim3(B_), dim3(256), 0, stream>>>(y, P, lens, A, out);
}